// Round 1
// baseline (965.721 us; speedup 1.0000x reference)
//
#include <hip/hip_runtime.h>
#include <stdint.h>

#define EDGES 200000
#define INF   128
#define HID   32
#define NHEAD 4
#define OUTF  128
#define MAXK  16

// padded combined-projection feature count: q(128) g(128) kv(256) b(4) pad(12)
#define NPAD  528
#define NTILES 33

typedef unsigned short u16;
typedef __attribute__((ext_vector_type(8))) short bf16x8;   // 8 bf16 = 4 VGPRs
typedef __attribute__((ext_vector_type(4))) float f32x4;

__device__ __forceinline__ u16 f2bf(float f) {   // RNE f32->bf16
  union { float f; uint32_t u; } v; v.f = f;
  uint32_t u = v.u;
  return (u16)((u + 0x7FFFu + ((u >> 16) & 1u)) >> 16);
}
__device__ __forceinline__ float bf2f(u16 s) {
  union { uint32_t u; float f; } v; v.u = ((uint32_t)s) << 16;
  return v.f;
}

// ---------------------------------------------------------------------------
// Kernel 1: repack all projection weights into one bf16 matrix Wc[NPAD][128]
//   n in [0,128):   q  (h=n>>5, d=n&31)  -> Wq flat row n
//   n in [128,256): g                    -> Wg flat row n-128
//   n in [256,512): kv (h=(n-256)>>6, c=(n-256)&63; c<32 -> k, else v)
//   n in [512,516): b  (Wb[h][0][:])
//   n in [516,528): zero pad
// plus Wout -> bf16 copy.
// ---------------------------------------------------------------------------
__global__ __launch_bounds__(256) void prep_kernel(
    const float* __restrict__ Wq, const float* __restrict__ Wk,
    const float* __restrict__ Wv, const float* __restrict__ Wb,
    const float* __restrict__ Wg, const float* __restrict__ Wout,
    u16* __restrict__ Wc, u16* __restrict__ Woutb)
{
  int t = blockIdx.x * 256 + threadIdx.x;
  if (t < NPAD * INF) {
    int n = t >> 7, k = t & 127;
    float v = 0.0f;
    if (n < 128)       v = Wq[n * 128 + k];
    else if (n < 256)  v = Wg[(n - 128) * 128 + k];
    else if (n < 512) {
      int m = n - 256, h = m >> 6, c = m & 63;
      v = (c < 32) ? Wk[(h * 32 + c) * 128 + k] : Wv[(h * 32 + (c - 32)) * 128 + k];
    } else if (n < 516) v = Wb[(n - 512) * 128 + k];
    Wc[t] = f2bf(v);
  } else if (t < NPAD * INF + OUTF * 128) {
    int u = t - NPAD * INF;
    Woutb[u] = f2bf(Wout[u]);
  }
}

// ---------------------------------------------------------------------------
// Kernel 2: projection GEMM  C[E x 528] = Z[E x 128] @ Wc^T   (bf16 MFMA)
// Block = 256 thr = 4 waves; M-tile 128 edges; each wave: 32 edges (2 sub-
// tiles of 16). A-frags loaded direct-from-global (f32->bf16 convert), held
// in regs; B-frags streamed from L2-hot Wc per n-tile. Epilogue scatters to
// qb/gb (bf16 [E][128]), kvb (bf16 [E][256]), bb (f32 [E][4]); sigmoid fused
// for g.
// mfma_f32_16x16x32_bf16 layouts (verified, learn_hip m89/m91):
//   A: lane = m + 16*blk, elems k = blk*8 + j
//   B: lane = n + 16*blk, elems k = blk*8 + j   (Wc is [n][k] row-major)
//   D: col(n) = lane&15, row(m) = (lane>>4)*4 + reg
// ---------------------------------------------------------------------------
__global__ __launch_bounds__(256) void proj_kernel(
    const float* __restrict__ Z, const u16* __restrict__ Wc,
    const float* __restrict__ bg,
    u16* __restrict__ qb, u16* __restrict__ gb,
    u16* __restrict__ kvb, float* __restrict__ bb)
{
  const int wid = threadIdx.x >> 6, lane = threadIdx.x & 63;
  const int ml = lane & 15, blk = lane >> 4;
  const long e0 = (long)blockIdx.x * 128 + wid * 32;

  bf16x8 afr[2][4];
#pragma unroll
  for (int s = 0; s < 2; ++s) {
    long er = e0 + s * 16 + ml; if (er > EDGES - 1) er = EDGES - 1;
    const float* zp = Z + er * INF + blk * 8;
#pragma unroll
    for (int kk = 0; kk < 4; ++kk) {
      float4 f0 = *(const float4*)(zp + kk * 32);
      float4 f1 = *(const float4*)(zp + kk * 32 + 4);
      bf16x8 a;
      a[0] = (short)f2bf(f0.x); a[1] = (short)f2bf(f0.y);
      a[2] = (short)f2bf(f0.z); a[3] = (short)f2bf(f0.w);
      a[4] = (short)f2bf(f1.x); a[5] = (short)f2bf(f1.y);
      a[6] = (short)f2bf(f1.z); a[7] = (short)f2bf(f1.w);
      afr[s][kk] = a;
    }
  }

  for (int nt = 0; nt < NTILES; ++nt) {
    bf16x8 bfr[4];
#pragma unroll
    for (int kk = 0; kk < 4; ++kk)
      bfr[kk] = *(const bf16x8*)(Wc + (nt * 16 + ml) * INF + kk * 32 + blk * 8);

    f32x4 acc[2];
    acc[0] = (f32x4){0.f, 0.f, 0.f, 0.f};
    acc[1] = (f32x4){0.f, 0.f, 0.f, 0.f};
#pragma unroll
    for (int kk = 0; kk < 4; ++kk) {
      acc[0] = __builtin_amdgcn_mfma_f32_16x16x32_bf16(afr[0][kk], bfr[kk], acc[0], 0, 0, 0);
      acc[1] = __builtin_amdgcn_mfma_f32_16x16x32_bf16(afr[1][kk], bfr[kk], acc[1], 0, 0, 0);
    }

    const int n = nt * 16 + ml;
#pragma unroll
    for (int s = 0; s < 2; ++s) {
#pragma unroll
      for (int r = 0; r < 4; ++r) {
        long e = e0 + s * 16 + blk * 4 + r;
        if (e >= EDGES) continue;
        float val = acc[s][r];
        if (n < 128) {
          qb[e * 128 + n] = f2bf(val);
        } else if (n < 256) {
          float sg = 1.0f / (1.0f + __expf(-(val + bg[n - 128])));
          gb[e * 128 + (n - 128)] = f2bf(sg);
        } else if (n < 512) {
          kvb[e * 256 + (n - 256)] = f2bf(val);
        } else if (n < 516) {
          bb[e * 4 + (n - 512)] = val;
        }
      }
    }
  }
}

// ---------------------------------------------------------------------------
// Kernel 3: gathered attention. One wave per edge. Lane = (h = lane>>4,
// d0 = (lane&15)*2, covers dims d0,d0+1), so q/g index = 2*lane.
// Scores: 16-lane xor-shuffle reduce per head; invalid (-1) neighbors get
// score 0 (and stay in softmax, matching reference), v-contrib zeroed.
// Writes x = g*att as bf16 to xb (aliases qb: per-edge read-before-write,
// data-dependent -> safe).
// ---------------------------------------------------------------------------
__global__ __launch_bounds__(256) void attn_kernel(
    const int* __restrict__ klist, const u16* qb,
    const u16* __restrict__ gb, const u16* __restrict__ kvb,
    const float* __restrict__ bb, u16* xb)
{
  const int wid = threadIdx.x >> 6;
  const int lane = threadIdx.x & 63;
  int e = blockIdx.x * 4 + wid;
  e = __builtin_amdgcn_readfirstlane(e);   // wave-uniform -> SGPR
  if (e >= EDGES) return;

  const int h = lane >> 4;
  const ushort2 q2 = *(const ushort2*)(qb + (size_t)e * 128 + 2 * lane);
  const ushort2 g2 = *(const ushort2*)(gb + (size_t)e * 128 + 2 * lane);
  const float q0 = bf2f(q2.x), q1 = bf2f(q2.y);
  const int kvo = h * 64 + (lane & 15) * 2;
  const float scale = 0.17677669529663687f;  // 1/sqrt(32)

  float sc[MAXK], v0a[MAXK], v1a[MAXK];
  const int* kl = klist + (size_t)e * 32;
#pragma unroll
  for (int nb = 0; nb < MAXK; ++nb) {
    const int ii = kl[nb];
    const int jj = kl[16 + nb];
    const bool valid = (ii >= 0);
    const int is = valid ? ii : 0;
    const int js = valid ? jj : 0;
    const u16* kvrow = kvb + (size_t)is * 256;
    ushort2 kk2 = *(const ushort2*)(kvrow + kvo);
    ushort2 vv2 = *(const ushort2*)(kvrow + kvo + 32);
    float p = q0 * bf2f(kk2.x) + q1 * bf2f(kk2.y);
    p += __shfl_xor(p, 1);
    p += __shfl_xor(p, 2);
    p += __shfl_xor(p, 4);
    p += __shfl_xor(p, 8);
    float bj = bb[(size_t)js * 4 + h];
    sc[nb]  = valid ? (scale * p + bj) : 0.0f;
    v0a[nb] = valid ? bf2f(vv2.x) : 0.0f;
    v1a[nb] = valid ? bf2f(vv2.y) : 0.0f;
  }

  float m = sc[0];
#pragma unroll
  for (int nb = 1; nb < MAXK; ++nb) m = fmaxf(m, sc[nb]);
  float s = 0.f, a0 = 0.f, a1 = 0.f;
#pragma unroll
  for (int nb = 0; nb < MAXK; ++nb) {
    float al = __expf(sc[nb] - m);
    s += al; a0 += al * v0a[nb]; a1 += al * v1a[nb];
  }
  float inv = 1.0f / s;
  ushort2 xo;
  xo.x = f2bf(bf2f(g2.x) * a0 * inv);
  xo.y = f2bf(bf2f(g2.y) * a1 * inv);
  *(ushort2*)(xb + (size_t)e * 128 + 2 * lane) = xo;
}

// ---------------------------------------------------------------------------
// Kernel 4: out[E x 128] = x[E x 128] @ Wout^T + bout   (bf16 MFMA, f32 out)
// Same tiling as proj_kernel; A-frags are direct bf16x8 loads from xb.
// ---------------------------------------------------------------------------
__global__ __launch_bounds__(256) void outgemm_kernel(
    const u16* xb, const u16* __restrict__ Woutb,
    const float* __restrict__ bout, float* __restrict__ out)
{
  const int wid = threadIdx.x >> 6, lane = threadIdx.x & 63;
  const int ml = lane & 15, blk = lane >> 4;
  const long e0 = (long)blockIdx.x * 128 + wid * 32;

  bf16x8 afr[2][4];
#pragma unroll
  for (int s = 0; s < 2; ++s) {
    long er = e0 + s * 16 + ml; if (er > EDGES - 1) er = EDGES - 1;
#pragma unroll
    for (int kk = 0; kk < 4; ++kk)
      afr[s][kk] = *(const bf16x8*)(xb + er * 128 + kk * 32 + blk * 8);
  }

#pragma unroll
  for (int nt = 0; nt < 8; ++nt) {
    bf16x8 bfr[4];
#pragma unroll
    for (int kk = 0; kk < 4; ++kk)
      bfr[kk] = *(const bf16x8*)(Woutb + (nt * 16 + ml) * 128 + kk * 32 + blk * 8);

    f32x4 acc[2];
    acc[0] = (f32x4){0.f, 0.f, 0.f, 0.f};
    acc[1] = (f32x4){0.f, 0.f, 0.f, 0.f};
#pragma unroll
    for (int kk = 0; kk < 4; ++kk) {
      acc[0] = __builtin_amdgcn_mfma_f32_16x16x32_bf16(afr[0][kk], bfr[kk], acc[0], 0, 0, 0);
      acc[1] = __builtin_amdgcn_mfma_f32_16x16x32_bf16(afr[1][kk], bfr[kk], acc[1], 0, 0, 0);
    }

    const int o = nt * 16 + ml;
    const float bo = bout[o];
#pragma unroll
    for (int s = 0; s < 2; ++s) {
#pragma unroll
      for (int r = 0; r < 4; ++r) {
        long e = e0 + s * 16 + blk * 4 + r;
        if (e < EDGES) out[e * 128 + o] = acc[s][r] + bo;
      }
    }
  }
}

// ---------------------------------------------------------------------------
extern "C" void kernel_launch(void* const* d_in, const int* in_sizes, int n_in,
                              void* d_out, int out_size, void* d_ws, size_t ws_size,
                              hipStream_t stream) {
  const float* Z     = (const float*)d_in[0];
  const int*   klist = (const int*)  d_in[1];   // JAX default x64-off -> int32
  const float* Wq    = (const float*)d_in[2];
  const float* Wk    = (const float*)d_in[3];
  const float* Wv    = (const float*)d_in[4];
  const float* Wb    = (const float*)d_in[5];
  const float* Wg    = (const float*)d_in[6];
  const float* bg    = (const float*)d_in[7];
  const float* Wout  = (const float*)d_in[8];
  const float* bout  = (const float*)d_in[9];
  float* out = (float*)d_out;

  // workspace layout (bytes, all 256-aligned); total ~208.2 MB
  char* ws = (char*)d_ws;
  u16*   Wc    = (u16*)(ws);                        //   528*128*2   = 135168
  u16*   Woutb = (u16*)(ws + 135168);               //   128*128*2   =  32768
  u16*   qb    = (u16*)(ws + 167936);               // E*128*2 = 51.2 MB (also xb)
  u16*   gb    = (u16*)(ws + 51367936);             // E*128*2 = 51.2 MB
  u16*   kvb   = (u16*)(ws + 102567936);            // E*256*2 = 102.4 MB
  float* bb    = (float*)(ws + 204967936);          // E*4*4   = 3.2 MB
  u16*   xb    = qb;                                // alias: per-edge RAW-safe

  prep_kernel<<<(NPAD * INF + OUTF * 128 + 255) / 256, 256, 0, stream>>>(
      Wq, Wk, Wv, Wb, Wg, Wout, Wc, Woutb);
  proj_kernel<<<(EDGES + 127) / 128, 256, 0, stream>>>(
      Z, Wc, bg, qb, gb, kvb, bb);
  attn_kernel<<<(EDGES + 3) / 4, 256, 0, stream>>>(
      klist, qb, gb, kvb, bb, xb);
  outgemm_kernel<<<(EDGES + 127) / 128, 256, 0, stream>>>(
      xb, Woutb, bout, out);
}

// Round 2
// 630.263 us; speedup vs baseline: 1.5323x; 1.5323x over previous
//
#include <hip/hip_runtime.h>
#include <stdint.h>

#define EDGES 200000
#define INF   128
#define HID   32
#define NHEAD 4
#define OUTF  128
#define MAXK  16

// padded combined-projection feature count: q(128) g(128) kv(256) b(4) pad(12)
#define NPAD  528
#define NTILES 33

typedef unsigned short u16;
typedef __attribute__((ext_vector_type(8))) short bf16x8;   // 8 bf16 = 4 VGPRs
typedef __attribute__((ext_vector_type(4))) float f32x4;

__device__ __forceinline__ u16 f2bf(float f) {   // RNE f32->bf16
  union { float f; uint32_t u; } v; v.f = f;
  uint32_t u = v.u;
  return (u16)((u + 0x7FFFu + ((u >> 16) & 1u)) >> 16);
}
__device__ __forceinline__ float bf2f(u16 s) {
  union { uint32_t u; float f; } v; v.u = ((uint32_t)s) << 16;
  return v.f;
}
__device__ __forceinline__ float bflo(uint32_t p) {   // low bf16 of packed pair
  union { uint32_t u; float f; } v; v.u = p << 16;
  return v.f;
}
__device__ __forceinline__ float bfhi(uint32_t p) {   // high bf16 of packed pair
  union { uint32_t u; float f; } v; v.u = p & 0xFFFF0000u;
  return v.f;
}

// DPP-based add within each 16-lane row (one head). bound_ctrl=1, full masks.
// 0xB1 = quad_perm [1,0,3,2] (xor1), 0x4E = quad_perm [2,3,0,1] (xor2),
// 0x141 = row_half_mirror (quad<->quad in 8), 0x140 = row_mirror (8<->8 in 16).
template <int CTRL>
__device__ __forceinline__ float dpp_add(float x) {
  int y = __builtin_amdgcn_update_dpp(0, __builtin_bit_cast(int, x),
                                      CTRL, 0xF, 0xF, true);
  return x + __builtin_bit_cast(float, y);
}
__device__ __forceinline__ float row16_sum(float x) {
  x = dpp_add<0xB1>(x);
  x = dpp_add<0x4E>(x);
  x = dpp_add<0x141>(x);
  x = dpp_add<0x140>(x);
  return x;
}

// ---------------------------------------------------------------------------
// Kernel 1: repack all projection weights into one bf16 matrix Wc[NPAD][128]
// ---------------------------------------------------------------------------
__global__ __launch_bounds__(256) void prep_kernel(
    const float* __restrict__ Wq, const float* __restrict__ Wk,
    const float* __restrict__ Wv, const float* __restrict__ Wb,
    const float* __restrict__ Wg, const float* __restrict__ Wout,
    u16* __restrict__ Wc, u16* __restrict__ Woutb)
{
  int t = blockIdx.x * 256 + threadIdx.x;
  if (t < NPAD * INF) {
    int n = t >> 7, k = t & 127;
    float v = 0.0f;
    if (n < 128)       v = Wq[n * 128 + k];
    else if (n < 256)  v = Wg[(n - 128) * 128 + k];
    else if (n < 512) {
      int m = n - 256, h = m >> 6, c = m & 63;
      v = (c < 32) ? Wk[(h * 32 + c) * 128 + k] : Wv[(h * 32 + (c - 32)) * 128 + k];
    } else if (n < 516) v = Wb[(n - 512) * 128 + k];
    Wc[t] = f2bf(v);
  } else if (t < NPAD * INF + OUTF * 128) {
    int u = t - NPAD * INF;
    Woutb[u] = f2bf(Wout[u]);
  }
}

// ---------------------------------------------------------------------------
// Kernel 2: projection GEMM  C[E x 528] = Z[E x 128] @ Wc^T   (bf16 MFMA)
// ---------------------------------------------------------------------------
__global__ __launch_bounds__(256) void proj_kernel(
    const float* __restrict__ Z, const u16* __restrict__ Wc,
    const float* __restrict__ bg,
    u16* __restrict__ qb, u16* __restrict__ gb,
    u16* __restrict__ kvb, float* __restrict__ bb)
{
  const int wid = threadIdx.x >> 6, lane = threadIdx.x & 63;
  const int ml = lane & 15, blk = lane >> 4;
  const long e0 = (long)blockIdx.x * 128 + wid * 32;

  bf16x8 afr[2][4];
#pragma unroll
  for (int s = 0; s < 2; ++s) {
    long er = e0 + s * 16 + ml; if (er > EDGES - 1) er = EDGES - 1;
    const float* zp = Z + er * INF + blk * 8;
#pragma unroll
    for (int kk = 0; kk < 4; ++kk) {
      float4 f0 = *(const float4*)(zp + kk * 32);
      float4 f1 = *(const float4*)(zp + kk * 32 + 4);
      bf16x8 a;
      a[0] = (short)f2bf(f0.x); a[1] = (short)f2bf(f0.y);
      a[2] = (short)f2bf(f0.z); a[3] = (short)f2bf(f0.w);
      a[4] = (short)f2bf(f1.x); a[5] = (short)f2bf(f1.y);
      a[6] = (short)f2bf(f1.z); a[7] = (short)f2bf(f1.w);
      afr[s][kk] = a;
    }
  }

  for (int nt = 0; nt < NTILES; ++nt) {
    bf16x8 bfr[4];
#pragma unroll
    for (int kk = 0; kk < 4; ++kk)
      bfr[kk] = *(const bf16x8*)(Wc + (nt * 16 + ml) * INF + kk * 32 + blk * 8);

    f32x4 acc[2];
    acc[0] = (f32x4){0.f, 0.f, 0.f, 0.f};
    acc[1] = (f32x4){0.f, 0.f, 0.f, 0.f};
#pragma unroll
    for (int kk = 0; kk < 4; ++kk) {
      acc[0] = __builtin_amdgcn_mfma_f32_16x16x32_bf16(afr[0][kk], bfr[kk], acc[0], 0, 0, 0);
      acc[1] = __builtin_amdgcn_mfma_f32_16x16x32_bf16(afr[1][kk], bfr[kk], acc[1], 0, 0, 0);
    }

    const int n = nt * 16 + ml;
#pragma unroll
    for (int s = 0; s < 2; ++s) {
#pragma unroll
      for (int r = 0; r < 4; ++r) {
        long e = e0 + s * 16 + blk * 4 + r;
        if (e >= EDGES) continue;
        float val = acc[s][r];
        if (n < 128) {
          qb[e * 128 + n] = f2bf(val);
        } else if (n < 256) {
          float sg = 1.0f / (1.0f + __expf(-(val + bg[n - 128])));
          gb[e * 128 + (n - 128)] = f2bf(sg);
        } else if (n < 512) {
          kvb[e * 256 + (n - 256)] = f2bf(val);
        } else if (n < 516) {
          bb[e * 4 + (n - 512)] = val;
        }
      }
    }
  }
}

// ---------------------------------------------------------------------------
// Kernel 3: gathered attention. One wave per edge, lane = (h=lane>>4, dims
// 2*(lane&15)..+1). Score reduce = 4 DPP adds within the head's 16-lane row
// (no LDS). Pass 1 keeps only sc[16] + masked packed vv[16] (32 VGPRs live)
// so neighbor chains overlap; pass 2 does softmax + weighted V.
// ---------------------------------------------------------------------------
__global__ __launch_bounds__(256) void attn_kernel(
    const int* __restrict__ klist, const u16* qb,
    const u16* __restrict__ gb, const u16* __restrict__ kvb,
    const float* __restrict__ bb, u16* xb)
{
  const int wid = threadIdx.x >> 6;
  const int lane = threadIdx.x & 63;
  int e = blockIdx.x * 4 + wid;
  e = __builtin_amdgcn_readfirstlane(e);   // wave-uniform -> SGPR
  if (e >= EDGES) return;

  const int h = lane >> 4;
  const uint32_t q2 = *(const uint32_t*)(qb + (size_t)e * 128 + 2 * lane);
  const uint32_t g2 = *(const uint32_t*)(gb + (size_t)e * 128 + 2 * lane);
  const float q0 = bflo(q2), q1 = bfhi(q2);
  const int kvo = h * 64 + (lane & 15) * 2;
  const float scale = 0.17677669529663687f;  // 1/sqrt(32)

  float sc[MAXK];
  uint32_t vvm[MAXK];
  const int* kl = klist + (size_t)e * 32;
#pragma unroll
  for (int nb = 0; nb < MAXK; ++nb) {
    const int ii = kl[nb];
    const int jj = kl[16 + nb];
    const bool valid = (ii >= 0);
    const int is = valid ? ii : 0;
    const int js = valid ? jj : 0;
    const u16* kvrow = kvb + (size_t)is * 256;
    uint32_t kki = *(const uint32_t*)(kvrow + kvo);        // k pair
    uint32_t vvi = *(const uint32_t*)(kvrow + kvo + 32);   // v pair (offset:64)
    float p = q0 * bflo(kki) + q1 * bfhi(kki);
    p = row16_sum(p);                                      // head-wide dot
    float bj = bb[(size_t)js * 4 + h];
    sc[nb]  = valid ? (scale * p + bj) : 0.0f;
    vvm[nb] = valid ? vvi : 0u;
  }

  float m = sc[0];
#pragma unroll
  for (int nb = 1; nb < MAXK; ++nb) m = fmaxf(m, sc[nb]);
  float s = 0.f, a0 = 0.f, a1 = 0.f;
#pragma unroll
  for (int nb = 0; nb < MAXK; ++nb) {
    float al = __expf(sc[nb] - m);
    s += al;
    a0 += al * bflo(vvm[nb]);
    a1 += al * bfhi(vvm[nb]);
  }
  float inv = 1.0f / s;
  u16 x0 = f2bf(bflo(g2) * a0 * inv);
  u16 x1 = f2bf(bfhi(g2) * a1 * inv);
  uint32_t xo = (uint32_t)x0 | ((uint32_t)x1 << 16);
  *(uint32_t*)(xb + (size_t)e * 128 + 2 * lane) = xo;
}

// ---------------------------------------------------------------------------
// Kernel 4: out[E x 128] = x[E x 128] @ Wout^T + bout   (bf16 MFMA, f32 out)
// ---------------------------------------------------------------------------
__global__ __launch_bounds__(256) void outgemm_kernel(
    const u16* xb, const u16* __restrict__ Woutb,
    const float* __restrict__ bout, float* __restrict__ out)
{
  const int wid = threadIdx.x >> 6, lane = threadIdx.x & 63;
  const int ml = lane & 15, blk = lane >> 4;
  const long e0 = (long)blockIdx.x * 128 + wid * 32;

  bf16x8 afr[2][4];
#pragma unroll
  for (int s = 0; s < 2; ++s) {
    long er = e0 + s * 16 + ml; if (er > EDGES - 1) er = EDGES - 1;
#pragma unroll
    for (int kk = 0; kk < 4; ++kk)
      afr[s][kk] = *(const bf16x8*)(xb + er * 128 + kk * 32 + blk * 8);
  }

#pragma unroll
  for (int nt = 0; nt < 8; ++nt) {
    bf16x8 bfr[4];
#pragma unroll
    for (int kk = 0; kk < 4; ++kk)
      bfr[kk] = *(const bf16x8*)(Woutb + (nt * 16 + ml) * 128 + kk * 32 + blk * 8);

    f32x4 acc[2];
    acc[0] = (f32x4){0.f, 0.f, 0.f, 0.f};
    acc[1] = (f32x4){0.f, 0.f, 0.f, 0.f};
#pragma unroll
    for (int kk = 0; kk < 4; ++kk) {
      acc[0] = __builtin_amdgcn_mfma_f32_16x16x32_bf16(afr[0][kk], bfr[kk], acc[0], 0, 0, 0);
      acc[1] = __builtin_amdgcn_mfma_f32_16x16x32_bf16(afr[1][kk], bfr[kk], acc[1], 0, 0, 0);
    }

    const int o = nt * 16 + ml;
    const float bo = bout[o];
#pragma unroll
    for (int s = 0; s < 2; ++s) {
#pragma unroll
      for (int r = 0; r < 4; ++r) {
        long e = e0 + s * 16 + blk * 4 + r;
        if (e < EDGES) out[e * 128 + o] = acc[s][r] + bo;
      }
    }
  }
}

// ---------------------------------------------------------------------------
extern "C" void kernel_launch(void* const* d_in, const int* in_sizes, int n_in,
                              void* d_out, int out_size, void* d_ws, size_t ws_size,
                              hipStream_t stream) {
  const float* Z     = (const float*)d_in[0];
  const int*   klist = (const int*)  d_in[1];
  const float* Wq    = (const float*)d_in[2];
  const float* Wk    = (const float*)d_in[3];
  const float* Wv    = (const float*)d_in[4];
  const float* Wb    = (const float*)d_in[5];
  const float* Wg    = (const float*)d_in[6];
  const float* bg    = (const float*)d_in[7];
  const float* Wout  = (const float*)d_in[8];
  const float* bout  = (const float*)d_in[9];
  float* out = (float*)d_out;

  char* ws = (char*)d_ws;
  u16*   Wc    = (u16*)(ws);                        //   528*128*2   = 135168
  u16*   Woutb = (u16*)(ws + 135168);               //   128*128*2   =  32768
  u16*   qb    = (u16*)(ws + 167936);               // E*128*2 = 51.2 MB (also xb)
  u16*   gb    = (u16*)(ws + 51367936);             // E*128*2 = 51.2 MB
  u16*   kvb   = (u16*)(ws + 102567936);            // E*256*2 = 102.4 MB
  float* bb    = (float*)(ws + 204967936);          // E*4*4   = 3.2 MB
  u16*   xb    = qb;                                // alias: per-edge RAW-safe

  prep_kernel<<<(NPAD * INF + OUTF * 128 + 255) / 256, 256, 0, stream>>>(
      Wq, Wk, Wv, Wb, Wg, Wout, Wc, Woutb);
  proj_kernel<<<(EDGES + 127) / 128, 256, 0, stream>>>(
      Z, Wc, bg, qb, gb, kvb, bb);
  attn_kernel<<<(EDGES + 3) / 4, 256, 0, stream>>>(
      klist, qb, gb, kvb, bb, xb);
  outgemm_kernel<<<(EDGES + 127) / 128, 256, 0, stream>>>(
      xb, Woutb, bout, out);
}